// Round 3
// baseline (219.002 us; speedup 1.0000x reference)
//
#include <hip/hip_runtime.h>
#include <hip/hip_bf16.h>
#include <cstdint>

// SelfAttention: B=4, S=4096, D=256, DK=256, causal, fp32 I/O, bf16 MFMA internals.
// Round 3: 32x32x16 MFMA (2x FLOP per LDS byte), 8-wave QBLK=256 blocks,
// global_load_lds staging with XOR-swizzled LDS (pre-swizzled global source),
// double-buffered K/V tiles (1 barrier/tile), defer-max softmax (THR=8),
// split-KV chunks of C=8 kv-tiles + combine kernel.
//
// ws layout:
//   [0)     Wt: 3 x 256 x 256 bf16 (Wq scaled by log2(e)/16)
//   [512K)  Q:  16384 x 256 bf16 row-major
//   [+8M)   K:  16384 x 256 bf16 row-major
//   [+8M)   Vt: [4][256][4096] bf16 (V transposed, plain s order)
//   [+8M)   part: [slot][256][256] bf16 partial O;  ml: [slot][256] float2

typedef __bf16 b8v __attribute__((ext_vector_type(8)));
typedef __bf16 b4v __attribute__((ext_vector_type(4)));
typedef float  f4v __attribute__((ext_vector_type(4)));
typedef float  f16v __attribute__((ext_vector_type(16)));
typedef int    i4v __attribute__((ext_vector_type(4)));

#define MFMA16(a, b, c) __builtin_amdgcn_mfma_f32_16x16x32_bf16((a), (b), (c), 0, 0, 0)
#define MFMA32(a, b, c) __builtin_amdgcn_mfma_f32_32x32x16_bf16((a), (b), (c), 0, 0, 0)

#define GLOAD_LDS(gsrc, ldst)                                                        \
  __builtin_amdgcn_global_load_lds((const __attribute__((address_space(1))) void*)(gsrc), \
                                   (__attribute__((address_space(3))) void*)(ldst), 16, 0, 0)

#define SCALE_Q 0.09016844005f  // log2(e) / sqrt(256)
#define MASKVAL -3.0e38f
#define M0VAL   -1.0e30f

static constexpr size_t WS_WT = 0;
static constexpr size_t WS_Q  = 524288;
static constexpr size_t WS_K  = WS_Q + 8388608;
static constexpr size_t WS_VT = WS_K + 8388608;
static constexpr size_t WS_PART = WS_VT + 8388608;  // 25,952,256

// ---------------------------------------------------------------- prep: W -> Wt bf16
__global__ void prep_wt(const float* __restrict__ Wq, const float* __restrict__ Wk,
                        const float* __restrict__ Wv, __bf16* __restrict__ wt) {
  int gid = blockIdx.x * blockDim.x + threadIdx.x;
  int w = gid >> 16, rem = gid & 65535;
  int c = rem >> 8, d = rem & 255;
  const float* W = (w == 0) ? Wq : (w == 1) ? Wk : Wv;
  float v = W[d * 256 + c];
  if (w == 0) v *= SCALE_Q;
  wt[gid] = (__bf16)v;  // wt[w][c][d] = W[d][c]
}

// ---------------------------------------------------------------- proj: x @ W -> Q,K,Vt
// 768 blocks: bid>>8 = which weight (0=Q,1=K,2=V), bid&255 = 64-row block.
__global__ void __launch_bounds__(256, 2) proj_qkv(
    const float* __restrict__ x, const __bf16* __restrict__ wt,
    __bf16* __restrict__ Qw, __bf16* __restrict__ Kw, __bf16* __restrict__ Vt) {
  __shared__ __bf16 w_lds[64][264];
  __shared__ __bf16 v_lds[64][72];
  const int tid = threadIdx.x;
  const int wv = tid >> 6, lane = tid & 63, c = lane & 15, g = lane >> 4;
  const int ww = blockIdx.x >> 8, rb = blockIdx.x & 255;
  const int rowbase = rb * 64;
  const int batch = rb >> 6, sblk = rb & 63;

  b8v xf[8];
  {
    const float* xr = x + (size_t)(rowbase + wv * 16 + c) * 256;
#pragma unroll
    for (int ks = 0; ks < 8; ++ks) {
      const float4 a0 = *reinterpret_cast<const float4*>(xr + 32 * ks + 8 * g);
      const float4 a1 = *reinterpret_cast<const float4*>(xr + 32 * ks + 8 * g + 4);
      b8v f;
      f[0] = (__bf16)a0.x; f[1] = (__bf16)a0.y; f[2] = (__bf16)a0.z; f[3] = (__bf16)a0.w;
      f[4] = (__bf16)a1.x; f[5] = (__bf16)a1.y; f[6] = (__bf16)a1.z; f[7] = (__bf16)a1.w;
      xf[ks] = f;
    }
  }
  const int srow = tid >> 2, sch = tid & 3;
  for (int ct = 0; ct < 4; ++ct) {
    __syncthreads();
    {
      const i4v* src = reinterpret_cast<const i4v*>(
          wt + ((size_t)(ww * 256 + ct * 64 + srow)) * 256 + sch * 64);
      i4v* dst = reinterpret_cast<i4v*>(&w_lds[srow][sch * 64]);
#pragma unroll
      for (int j = 0; j < 8; ++j) dst[j] = src[j];
    }
    __syncthreads();
    f4v pacc[4];
#pragma unroll
    for (int i = 0; i < 4; ++i) pacc[i] = (f4v){0.f, 0.f, 0.f, 0.f};
#pragma unroll
    for (int ks = 0; ks < 8; ++ks) {
#pragma unroll
      for (int nf = 0; nf < 4; ++nf) {
        b8v wf = *reinterpret_cast<const b8v*>(&w_lds[16 * nf + c][32 * ks + 8 * g]);
        pacc[nf] = MFMA16(xf[ks], wf, pacc[nf]);
      }
    }
    if (ww < 2) {
      __bf16* o = (ww == 0) ? Qw : Kw;
      const int row0 = rowbase + wv * 16 + 4 * g;
#pragma unroll
      for (int nf = 0; nf < 4; ++nf) {
        const int col = ct * 64 + 16 * nf + c;
#pragma unroll
        for (int r = 0; r < 4; ++r)
          o[(size_t)(row0 + r) * 256 + col] = (__bf16)pacc[nf][r];
      }
    } else {
      // V: plain s order now (s_local = 16*wv + 4*g + r)
      const int sp = 16 * wv + 4 * g;
#pragma unroll
      for (int nf = 0; nf < 4; ++nf) {
        b4v pk;
        pk[0] = (__bf16)pacc[nf][0]; pk[1] = (__bf16)pacc[nf][1];
        pk[2] = (__bf16)pacc[nf][2]; pk[3] = (__bf16)pacc[nf][3];
        *reinterpret_cast<b4v*>(&v_lds[16 * nf + c][sp]) = pk;
      }
      __syncthreads();
      {
        const int dd = tid >> 2, ch = tid & 3;
        const b8v* sp8 = reinterpret_cast<const b8v*>(&v_lds[dd][ch * 16]);
        __bf16* dst =
            Vt + ((size_t)(batch * 256 + ct * 64 + dd)) * 4096 + sblk * 64 + ch * 16;
        reinterpret_cast<b8v*>(dst)[0] = sp8[0];
        reinterpret_cast<b8v*>(dst)[1] = sp8[1];
      }
    }
  }
}

// ---------------------------------------------------------------- flash attention
// 8 waves x 32 q-rows (QBLK=256), KVBLK=64, 32x32x16 MFMA, swapped QK^T.
// LDS: K[64][256] + V[256][64] double-buffered, 16B-chunk XOR swizzle by row&7
// (applied on the global source so global_load_lds stays linear). 1 barrier/tile.
__global__ void __launch_bounds__(512, 2) attn_fwd(
    const __bf16* __restrict__ Qw, const __bf16* __restrict__ Kw,
    const __bf16* __restrict__ Vt, float* __restrict__ out,
    __bf16* __restrict__ part, float* __restrict__ ml, int sc, int SPB) {
  extern __shared__ char smem[];
  char* K0 = smem;
  char* V0 = smem + 32768;
  char* K1 = smem + 65536;
  char* V1 = smem + 98304;
  float* bc = reinterpret_cast<float*>(smem + 131072);  // [8][32] broadcast

  const int tid = threadIdx.x;
  const int wv = tid >> 6, lane = tid & 63;
  const int q5 = lane & 31, hi = lane >> 5, x7 = q5 & 7;
  const int C = 1 << sc;

  // decode block -> (bb, qb desc, ch)
  const int bb = blockIdx.x & 3;
  int s = blockIdx.x >> 2;
  int qb = 0, ch = 0;
  for (int j = 15; j >= 0; --j) {
    const int n = (4 * j + 4 + C - 1) >> sc;
    if (s < n) { qb = j; ch = s; break; }
    s -= n;
  }
  int prefA = 0;
  for (int j = 0; j < qb; ++j) prefA += (4 * j + 4 + C - 1) >> sc;
  const int slot = bb * SPB + prefA + ch;
  const int nch = (4 * qb + 4 + C - 1) >> sc;
  const int t0 = ch << sc;
  const int t1 = min(4 * qb + 3, t0 + C - 1);

  // Q fragments: 16 k-steps, row = qb*256 + wv*32 + q5
  b8v qf[16];
  {
    const __bf16* qr =
        Qw + ((size_t)(bb * 4096 + qb * 256 + wv * 32 + q5)) * 256 + 8 * hi;
#pragma unroll
    for (int ks = 0; ks < 16; ++ks) qf[ks] = *reinterpret_cast<const b8v*>(qr + ks * 16);
  }
  const __bf16* Kg = Kw + (size_t)bb * 4096 * 256;
  const __bf16* Vg = Vt + (size_t)bb * 256 * 4096;

  // stage tile t into (Kd, Vd); LDS linear, global source pre-swizzled
  auto stage = [&](char* Kd, char* Vd, int t) {
#pragma unroll
    for (int i = 0; i < 4; ++i) {
      const int n = i * 512 + wv * 64 + lane;
      const int row = n >> 5, cp = n & 31;
      const __bf16* src = Kg + (size_t)(t * 64 + row) * 256 + ((cp ^ (row & 7)) << 3);
      GLOAD_LDS(src, Kd + (size_t)(i * 512 + wv * 64) * 16);
    }
#pragma unroll
    for (int i = 0; i < 4; ++i) {
      const int n = i * 512 + wv * 64 + lane;
      const int row = n >> 3, cp = n & 7;
      const __bf16* src = Vg + (size_t)row * 4096 + t * 64 + ((cp ^ (row & 7)) << 3);
      GLOAD_LDS(src, Vd + (size_t)(i * 512 + wv * 64) * 16);
    }
  };

  stage(K0, V0, t0);
  __syncthreads();

  f16v acc[8];
#pragma unroll
  for (int i = 0; i < 8; ++i)
#pragma unroll
    for (int j = 0; j < 16; ++j) acc[i][j] = 0.f;
  float m = M0VAL, lsum = 0.f;
  const int qg = qb * 256 + wv * 32 + q5;

  for (int t = t0; t <= t1; ++t) {
    const int cur = (t - t0) & 1;
    const char* Kc = cur ? K1 : K0;
    const char* Vc = cur ? V1 : V0;
    if (t < t1) stage(cur ? K0 : K1, cur ? V0 : V1, t + 1);

    // S^T = K * Q^T : sc0 rows 0-31 of k-tile, sc1 rows 32-63; col = q5
    f16v s0, s1;
#pragma unroll
    for (int j = 0; j < 16; ++j) { s0[j] = 0.f; s1[j] = 0.f; }
    const char* kb0 = Kc + q5 * 512;
    const char* kb1 = kb0 + 16384;
    __builtin_amdgcn_s_setprio(1);
#pragma unroll
    for (int ks = 0; ks < 16; ++ks) {
      const int co = (((ks << 1) | hi) ^ x7) << 4;
      const b8v k0 = *reinterpret_cast<const b8v*>(kb0 + co);
      const b8v k1 = *reinterpret_cast<const b8v*>(kb1 + co);
      s0 = MFMA32(k0, qf[ks], s0);
      s1 = MFMA32(k1, qf[ks], s1);
    }
    __builtin_amdgcn_s_setprio(0);

    // causal mask (k_global > q_global)
    if (t * 64 + 63 > qb * 256 + wv * 32) {
#pragma unroll
      for (int reg = 0; reg < 16; ++reg) {
        const int R = (reg & 3) + 8 * (reg >> 2) + 4 * hi;
        if (t * 64 + R > qg) s0[reg] = MASKVAL;
        if (t * 64 + 32 + R > qg) s1[reg] = MASKVAL;
      }
    }
    // lane-local max (own 32 values)
    float p0 = s0[0], p1 = s0[1], p2 = s0[2], p3 = s0[3];
#pragma unroll
    for (int j = 4; j < 16; j += 4) {
      p0 = fmaxf(p0, s0[j]); p1 = fmaxf(p1, s0[j + 1]);
      p2 = fmaxf(p2, s0[j + 2]); p3 = fmaxf(p3, s0[j + 3]);
    }
#pragma unroll
    for (int j = 0; j < 16; j += 4) {
      p0 = fmaxf(p0, s1[j]); p1 = fmaxf(p1, s1[j + 1]);
      p2 = fmaxf(p2, s1[j + 2]); p3 = fmaxf(p3, s1[j + 3]);
    }
    const float pm = fmaxf(fmaxf(p0, p1), fmaxf(p2, p3));

    if (!__all(pm - m <= 8.0f)) {  // full path (rare after first tile)
      const float pm2 = fmaxf(pm, __shfl_xor(pm, 32));
      const float mnew = fmaxf(m, pm2);
      const float fac = exp2f(m - mnew);
      bc[wv * 32 + q5] = fac;
      lsum *= fac;
      m = mnew;
#pragma unroll
      for (int reg = 0; reg < 16; ++reg) {
        const float fr = bc[wv * 32 + ((reg & 3) + 8 * (reg >> 2) + 4 * hi)];
#pragma unroll
        for (int db = 0; db < 8; ++db) acc[db][reg] *= fr;
      }
    }
    // P = exp2(S - m), lane-partial sum
#pragma unroll
    for (int j = 0; j < 16; ++j) {
      s0[j] = exp2f(s0[j] - m);
      s1[j] = exp2f(s1[j] - m);
    }
    {
      float u0 = 0.f, u1 = 0.f, u2 = 0.f, u3 = 0.f;
#pragma unroll
      for (int j = 0; j < 16; j += 4) {
        u0 += s0[j]; u1 += s0[j + 1]; u2 += s0[j + 2]; u3 += s0[j + 3];
        u0 += s1[j]; u1 += s1[j + 1]; u2 += s1[j + 2]; u3 += s1[j + 3];
      }
      lsum += (u0 + u1) + (u2 + u3);
    }
    // pack P -> bf16 quads: a0/a1[m], m = 4*rb + (reg>>2), values s_rb[4*(m&3)+r]
    unsigned a0[8], a1[8];
#pragma unroll
    for (int mb = 0; mb < 4; ++mb) {
      b4v pk;
      pk[0] = (__bf16)s0[4 * mb]; pk[1] = (__bf16)s0[4 * mb + 1];
      pk[2] = (__bf16)s0[4 * mb + 2]; pk[3] = (__bf16)s0[4 * mb + 3];
      const uint2 u = *reinterpret_cast<uint2*>(&pk);
      a0[mb] = u.x; a1[mb] = u.y;
    }
#pragma unroll
    for (int mb = 0; mb < 4; ++mb) {
      b4v pk;
      pk[0] = (__bf16)s1[4 * mb]; pk[1] = (__bf16)s1[4 * mb + 1];
      pk[2] = (__bf16)s1[4 * mb + 2]; pk[3] = (__bf16)s1[4 * mb + 3];
      const uint2 u = *reinterpret_cast<uint2*>(&pk);
      a0[4 + mb] = u.x; a1[4 + mb] = u.y;
    }
    // O += P * V : exchange halves with partner lane (l^32), assemble A-frags
#pragma unroll
    for (int ks = 0; ks < 4; ++ks) {
      const unsigned x0 = (unsigned)__shfl_xor((int)a0[2 * ks], 32);
      const unsigned x1 = (unsigned)__shfl_xor((int)a1[2 * ks], 32);
      const unsigned y0 = (unsigned)__shfl_xor((int)a0[2 * ks + 1], 32);
      const unsigned y1 = (unsigned)__shfl_xor((int)a1[2 * ks + 1], 32);
      i4v wi;
      wi[0] = hi ? (int)y0 : (int)a0[2 * ks];
      wi[1] = hi ? (int)y1 : (int)a1[2 * ks];
      wi[2] = hi ? (int)a0[2 * ks + 1] : (int)x0;
      wi[3] = hi ? (int)a1[2 * ks + 1] : (int)x1;
      const b8v pa = *reinterpret_cast<b8v*>(&wi);
      const int cov = (((ks << 1) | hi) ^ x7) << 4;
      const char* vb = Vc + q5 * 128 + cov;
      __builtin_amdgcn_s_setprio(1);
#pragma unroll
      for (int db = 0; db < 8; ++db) {
        const b8v vf = *reinterpret_cast<const b8v*>(vb + db * 4096);
        acc[db] = MFMA32(pa, vf, acc[db]);
      }
      __builtin_amdgcn_s_setprio(0);
    }
    __syncthreads();  // next tile staged (drains vmcnt), LDS reads done
  }

  lsum += __shfl_xor(lsum, 32);
  if (nch == 1) {  // direct normalized output
    const float inv = 1.f / lsum;
    bc[wv * 32 + q5] = inv;
#pragma unroll
    for (int reg = 0; reg < 16; ++reg) {
      const int R = (reg & 3) + 8 * (reg >> 2) + 4 * hi;
      const float ivr = bc[wv * 32 + R];
      float* orow = out + ((size_t)(bb * 4096 + qb * 256 + wv * 32 + R)) * 256 + q5;
#pragma unroll
      for (int db = 0; db < 8; ++db) orow[db * 32] = acc[db][reg] * ivr;
    }
  } else {  // partial
    __bf16* pbase = part + (size_t)slot * 65536;
#pragma unroll
    for (int reg = 0; reg < 16; ++reg) {
      const int R = (reg & 3) + 8 * (reg >> 2) + 4 * hi;
      __bf16* prow = pbase + (size_t)(wv * 32 + R) * 256 + q5;
#pragma unroll
      for (int db = 0; db < 8; ++db) prow[db * 32] = (__bf16)acc[db][reg];
    }
    if (hi == 0) {
      float2* ml2 = reinterpret_cast<float2*>(ml);
      ml2[(size_t)slot * 256 + wv * 32 + q5] = make_float2(m, lsum);
    }
  }
}

// ---------------------------------------------------------------- combine partials
__global__ void __launch_bounds__(256) combine_k(
    const __bf16* __restrict__ part, const float* __restrict__ ml,
    float* __restrict__ out, int sc, int qbmin, int SPB) {
  const int bid = blockIdx.x;
  const int bb = bid & 3, qb = qbmin + (bid >> 2);
  const int C = 1 << sc;
  const int nch = (4 * qb + 4 + C - 1) >> sc;
  int pref = 0;
  for (int j = 0; j < qb; ++j) pref += (4 * j + 4 + C - 1) >> sc;
  const int sb = bb * SPB + pref;
  const int t = threadIdx.x;
  const int r8 = t >> 3, dc = (t & 7) << 5;
  const float2* ml2 = reinterpret_cast<const float2*>(ml);
  for (int rr = 0; rr < 8; ++rr) {
    const int row = rr * 32 + r8;
    float mv[8], lv[8], mx = MASKVAL;
#pragma unroll
    for (int cc = 0; cc < 8; ++cc) {
      if (cc < nch) {
        const float2 p = ml2[(size_t)(sb + cc) * 256 + row];
        mv[cc] = p.x; lv[cc] = p.y; mx = fmaxf(mx, p.x);
      } else { mv[cc] = MASKVAL; lv[cc] = 0.f; }
    }
    float den = 0.f, wt_[8];
#pragma unroll
    for (int cc = 0; cc < 8; ++cc) {
      const float w = exp2f(mv[cc] - mx);
      wt_[cc] = w;
      den += w * lv[cc];
    }
    const float inv = 1.f / den;
    float o[32];
#pragma unroll
    for (int j = 0; j < 32; ++j) o[j] = 0.f;
    for (int cc = 0; cc < nch; ++cc) {
      const float w = wt_[cc] * inv;
      const b8v* src = reinterpret_cast<const b8v*>(
          part + ((size_t)(sb + cc) * 256 + row) * 256 + dc);
#pragma unroll
      for (int k = 0; k < 4; ++k) {
        const b8v v = src[k];
#pragma unroll
        for (int j = 0; j < 8; ++j) o[k * 8 + j] += w * (float)v[j];
      }
    }
    float* dst = out + ((size_t)(bb * 4096 + qb * 256 + row)) * 256 + dc;
#pragma unroll
    for (int k = 0; k < 8; ++k) {
      const f4v ov = {o[4 * k], o[4 * k + 1], o[4 * k + 2], o[4 * k + 3]};
      *reinterpret_cast<f4v*>(dst + 4 * k) = ov;
    }
  }
}

// ---------------------------------------------------------------- launch
extern "C" void kernel_launch(void* const* d_in, const int* in_sizes, int n_in,
                              void* d_out, int out_size, void* d_ws, size_t ws_size,
                              hipStream_t stream) {
  const float* x  = reinterpret_cast<const float*>(d_in[0]);
  const float* Wq = reinterpret_cast<const float*>(d_in[1]);
  const float* Wk = reinterpret_cast<const float*>(d_in[2]);
  const float* Wv = reinterpret_cast<const float*>(d_in[3]);
  char* ws = reinterpret_cast<char*>(d_ws);
  __bf16* wt = reinterpret_cast<__bf16*>(ws + WS_WT);
  __bf16* Qw = reinterpret_cast<__bf16*>(ws + WS_Q);
  __bf16* Kw = reinterpret_cast<__bf16*>(ws + WS_K);
  __bf16* Vt = reinterpret_cast<__bf16*>(ws + WS_VT);
  float* out = reinterpret_cast<float*>(d_out);

  // pick chunk size (in 64-row kv tiles, C = 1<<sc) from available scratch
  int scSel = 6, SPB = 16;
  for (int scc = 3; scc <= 5; ++scc) {
    int sl = 0;
    for (int j = 0; j < 16; ++j) sl += (4 * j + 4 + (1 << scc) - 1) >> scc;
    const size_t need = WS_PART + (size_t)4 * sl * 131072 + (size_t)4 * sl * 2048;
    if (ws_size >= need) { scSel = scc; SPB = sl; break; }
  }
  __bf16* part = reinterpret_cast<__bf16*>(ws + WS_PART);
  float* mlp = (scSel < 6)
                   ? reinterpret_cast<float*>(ws + WS_PART + (size_t)4 * SPB * 131072)
                   : reinterpret_cast<float*>(ws);

  prep_wt<<<768, 256, 0, stream>>>(Wq, Wk, Wv, wt);
  proj_qkv<<<768, 256, 0, stream>>>(x, wt, Qw, Kw, Vt);

  constexpr int kSmem = 131072 + 1024;
  (void)hipFuncSetAttribute(reinterpret_cast<const void*>(attn_fwd),
                            hipFuncAttributeMaxDynamicSharedMemorySize, kSmem);
  attn_fwd<<<4 * SPB, 512, kSmem, stream>>>(Qw, Kw, Vt, out, part, mlp, scSel, SPB);

  const int qbmin = 1 << (scSel - 2);
  if (qbmin < 16)
    combine_k<<<4 * (16 - qbmin), 256, 0, stream>>>(part, mlp, out, scSel, qbmin, SPB);
}